// Round 5
// baseline (1883.056 us; speedup 1.0000x reference)
//
#include <hip/hip_runtime.h>
#include <stdint.h>

#define BB 128
#define SS 2048
#define TT 128
#define NSEG 32
#define SEGK 64

#define TRP 129              // trans row stride in LDS (129 % 32 == 1)
#define SPITCH 160           // state buffer stride (dwords), padded: PI(127)=155
#define PI(i) ((i) + (((i) >> 4) << 2))   // pad 4 dwords per 16: i + (i/16)*4

typedef float f32x4 __attribute__((ext_vector_type(4)));

// raw barrier: drain LDS ops only (NOT vmcnt -> prefetch loads stay in flight)
#define BAR() asm volatile("s_waitcnt lgkmcnt(0)\n\ts_barrier" ::: "memory")
#define PIN(x) asm volatile("" : "+v"(x))

template <int CTRL>
__device__ __forceinline__ float dppf(float x) {
    return __int_as_float(__builtin_amdgcn_update_dpp(0, __float_as_int(x), CTRL, 0xF, 0xF, true));
}
template <int CTRL>
__device__ __forceinline__ int dppi(int x) {
    return __builtin_amdgcn_update_dpp(0, x, CTRL, 0xF, 0xF, true);
}
// DPP ctrl: 0xB1 = quad_perm[1,0,3,2] (xor1), 0x4E = quad_perm[2,3,0,1] (xor2),
//           0x141 = row_half_mirror (lane -> lane^7 within 8) — {1,2,7} spans the 8-group.

__device__ __forceinline__ f32x4 fmax4(f32x4 a, f32x4 b) {
    f32x4 r;
    r.x = fmaxf(a.x, b.x); r.y = fmaxf(a.y, b.y);
    r.z = fmaxf(a.z, b.z); r.w = fmaxf(a.w, b.w);
    return r;
}

// ---------------- main kernel: 256 blocks. role 0 = viterbi, role 1 = forward+num.
// 256 threads = 4 waves. wave w owns j in [32w, 32w+32).
// lane: ig = lane&7 -> i-range [16*ig, 16*ig+16); jd = lane>>3 -> j quad j0 = w*32+jd*4.
__attribute__((amdgpu_flat_work_group_size(256, 256)))
__attribute__((amdgpu_waves_per_eu(1, 1)))
__global__ void crf_mainX(const float* __restrict__ logit,
                          const int* __restrict__ seq_lens,
                          const float* __restrict__ trans,
                          const float* __restrict__ startT,
                          const float* __restrict__ endT,
                          const int* __restrict__ target,
                          uint8_t* __restrict__ histG,
                          float* __restrict__ scr_logZ,
                          int* __restrict__ scr_last,
                          float* __restrict__ scr_num)
{
    extern __shared__ float smem[];
    float* transLDS = smem;                          // 16512
    float* stateLDS = smem + 16512;                  // 2 * SPITCH = 320
    float* ringLDS  = smem + 16832;                  // 4
    float* redLDS   = smem + 16836;                  // 8
    int*   redILDS  = (int*)(smem + 16844);          // 4
    float* sumLDS   = smem + 16848;                  // 4

    const int bid  = blockIdx.x;
    const int role = bid >> 7;
    const int b    = bid & (BB - 1);
    const int tid  = threadIdx.x;
    const int w    = tid >> 6;
    const int lane = tid & 63;
    const int ig   = lane & 7;
    const int jd   = lane >> 3;
    const int j0   = w * 32 + jd * 4;
    const int ibase = ig * 16;
    const int L = seq_lens[b];
    const size_t lbase = (size_t)b * (SS * TT);

    // stage transitions into padded LDS (stride TRP)
    for (int m = tid; m < TT * TT; m += 256)
        transLDS[(m >> 7) * TRP + (m & 127)] = trans[m];
    __syncthreads();

    // depth-3 prefetch of logit rows (float4 per lane, 8 ig-lanes dedup)
    f32x4 e1 = {0,0,0,0}, e2, e3;
    if (L > 1) e1 = *(const f32x4*)(logit + lbase + (size_t)TT + j0);
    e2 = (L > 2) ? *(const f32x4*)(logit + lbase + 2 * (size_t)TT + j0) : e1;
    e3 = (L > 3) ? *(const f32x4*)(logit + lbase + 3 * (size_t)TT + j0) : e2;

    // init alpha0 quad
    const f32x4 st4 = *(const f32x4*)(startT + j0);
    const f32x4 l04 = *(const f32x4*)(logit + lbase + j0);
    const f32x4 a04 = st4 + l04;

    if (role == 0) {
        // =================== VITERBI ===================
        f32x4 tj[4][4];  // T[ibase+4c+s][j0+q]
#pragma unroll
        for (int q = 0; q < 4; ++q)
#pragma unroll
            for (int c = 0; c < 4; ++c) {
                tj[q][c].x = transLDS[(ibase + c * 4 + 0) * TRP + (j0 + q)];
                tj[q][c].y = transLDS[(ibase + c * 4 + 1) * TRP + (j0 + q)];
                tj[q][c].z = transLDS[(ibase + c * 4 + 2) * TRP + (j0 + q)];
                tj[q][c].w = transLDS[(ibase + c * 4 + 3) * TRP + (j0 + q)];
                PIN(tj[q][c]);
            }
        if (ig == 0) *(f32x4*)(stateLDS + PI(j0)) = a04;
        __syncthreads();

        uint8_t* hb = histG + (size_t)b * (SS * TT);

        for (int t = 1; t < L; ++t) {
            const int cur = (t - 1) & 1, nxt = t & 1;
            const f32x4 e4 = e1; e1 = e2; e2 = e3;
            const int tn = (t + 3 < L) ? (t + 3) : (L - 1);
            e3 = *(const f32x4*)(logit + lbase + (size_t)tn * TT + j0);

            // state chunk for my i-range (conflict-free: 8 addrs hit 32 distinct banks)
            const f32x4* sq = (const f32x4*)(stateLDS + cur * SPITCH + 20 * ig);
            f32x4 s0 = sq[0], s1 = sq[1], s2 = sq[2], s3 = sq[3];

            float va[4];
            int   pidx[4];
#pragma unroll
            for (int q = 0; q < 4; ++q) {
                f32x4 P[4];
                P[0] = s0 + tj[q][0];
                P[1] = s1 + tj[q][1];
                P[2] = s2 + tj[q][2];
                P[3] = s3 + tj[q][3];
                f32x4 m4 = fmax4(fmax4(P[0], P[1]), fmax4(P[2], P[3]));
                float M = fmaxf(fmaxf(m4.x, m4.y), fmaxf(m4.z, m4.w));
                M = fmaxf(M, dppf<0xB1>(M));
                M = fmaxf(M, dppf<0x4E>(M));
                M = fmaxf(M, dppf<0x141>(M));
                const float e = (q == 0) ? e4.x : (q == 1) ? e4.y : (q == 2) ? e4.z : e4.w;
                const float v = M + e;   // exact reference max value
                // exact first-index: descending reg scan of (p+e)==v
                int idx = 0x7fffffff;
                const f32x4 esp = {e, e, e, e};
#pragma unroll
                for (int c = 3; c >= 0; --c) {
                    f32x4 qv = P[c] + esp;
                    idx = (qv.w == v) ? (ibase + c * 4 + 3) : idx;
                    idx = (qv.z == v) ? (ibase + c * 4 + 2) : idx;
                    idx = (qv.y == v) ? (ibase + c * 4 + 1) : idx;
                    idx = (qv.x == v) ? (ibase + c * 4 + 0) : idx;
                }
                int o;
                o = dppi<0xB1>(idx);  idx = (o < idx) ? o : idx;
                o = dppi<0x4E>(idx);  idx = (o < idx) ? o : idx;
                o = dppi<0x141>(idx); idx = (o < idx) ? o : idx;
                va[q] = v;
                pidx[q] = idx;
            }
            if (ig == 0) {
                f32x4 vv = {va[0], va[1], va[2], va[3]};
                *(f32x4*)(stateLDS + nxt * SPITCH + PI(j0)) = vv;
            }
            if (ig == 1) {
                uint32_t pk = (uint32_t)pidx[0] | ((uint32_t)pidx[1] << 8) |
                              ((uint32_t)pidx[2] << 16) | ((uint32_t)pidx[3] << 24);
                *(uint32_t*)(hb + (size_t)t * TT + j0) = pk;
            }
            BAR();
        }

        // ---- last_tag = argmax_j(score + end), first-index ----
        const int fin = (L - 1) & 1;
        if (tid < 128) {
            float lv = stateLDS[fin * SPITCH + PI(tid)] + endT[tid];
            int li = tid;
#pragma unroll
            for (int off = 1; off < 64; off <<= 1) {
                float ov = __shfl_xor(lv, off);
                int oi = __shfl_xor(li, off);
                if (ov > lv || (ov == lv && oi < li)) { lv = ov; li = oi; }
            }
            if ((tid & 63) == 0) { redLDS[tid >> 6] = lv; redILDS[tid >> 6] = li; }
        }
        __syncthreads();
        if (tid == 0) {
            int lt = (redLDS[1] > redLDS[0] ||
                      (redLDS[1] == redLDS[0] && redILDS[1] < redILDS[0]))
                     ? redILDS[1] : redILDS[0];
            scr_last[b] = lt;
        }
        // ---- identity fill of hist rows [L, SS) ----
        const int colq = (tid & 7) * 16;
        const uint32_t w0 = 0x03020100u + 0x01010101u * (uint32_t)colq;
        const uint4 pat = make_uint4(w0, w0 + 0x04040404u, w0 + 0x08080808u, w0 + 0x0C0C0C0Cu);
        for (int t0 = L; t0 < SS; t0 += 32) {
            int t = t0 + (tid >> 3);
            if (t < SS) *(uint4*)(hb + (size_t)t * TT + colq) = pat;
        }
    } else {
        // =================== FORWARD (logZ) ===================
        f32x4 tE[4][4];  // exp(T[ibase+4c+s][j0+q])
#pragma unroll
        for (int q = 0; q < 4; ++q)
#pragma unroll
            for (int c = 0; c < 4; ++c) {
                tE[q][c].x = __expf(transLDS[(ibase + c * 4 + 0) * TRP + (j0 + q)]);
                tE[q][c].y = __expf(transLDS[(ibase + c * 4 + 1) * TRP + (j0 + q)]);
                tE[q][c].z = __expf(transLDS[(ibase + c * 4 + 2) * TRP + (j0 + q)]);
                tE[q][c].w = __expf(transLDS[(ibase + c * 4 + 3) * TRP + (j0 + q)]);
                PIN(tE[q][c]);
            }
        const float R0 = startT[0] + logit[lbase];  // alpha0[0], uniform
        float aa[4] = {a04.x, a04.y, a04.z, a04.w};
        if (ig == 0) {
            f32x4 ex = {__expf(a04.x - R0), __expf(a04.y - R0),
                        __expf(a04.z - R0), __expf(a04.w - R0)};
            *(f32x4*)(stateLDS + PI(j0)) = ex;
        }
        if (tid < 4) ringLDS[tid] = R0;
        __syncthreads();

        for (int t = 1; t < L; ++t) {
            const int cur = (t - 1) & 1, nxt = t & 1;
            const float Rcons = ringLDS[(t - 3) & 3];  // shift used by aexp[cur]
            const float Rpub  = ringLDS[(t - 2) & 3];  // shift for publishing aexp[nxt]
            const f32x4 e4 = e1; e1 = e2; e2 = e3;
            const int tn = (t + 3 < L) ? (t + 3) : (L - 1);
            e3 = *(const f32x4*)(logit + lbase + (size_t)tn * TT + j0);

            const f32x4* aq = (const f32x4*)(stateLDS + cur * SPITCH + 20 * ig);
            f32x4 s0 = aq[0], s1 = aq[1], s2 = aq[2], s3 = aq[3];

            float pv[4];
#pragma unroll
            for (int q = 0; q < 4; ++q) {
                f32x4 acc = s0 * tE[q][0];
                acc = s1 * tE[q][1] + acc;
                acc = s2 * tE[q][2] + acc;
                acc = s3 * tE[q][3] + acc;
                float S = (acc.x + acc.y) + (acc.z + acc.w);
                S += dppf<0xB1>(S);
                S += dppf<0x4E>(S);
                S += dppf<0x141>(S);
                const float e = (q == 0) ? e4.x : (q == 1) ? e4.y : (q == 2) ? e4.z : e4.w;
                const float alpha = e + Rcons + __logf(S);
                aa[q] = alpha;
                pv[q] = __expf(alpha - Rpub);
            }
            if (ig == 0) {
                f32x4 pp = {pv[0], pv[1], pv[2], pv[3]};
                *(f32x4*)(stateLDS + nxt * SPITCH + PI(j0)) = pp;
            }
            if (tid == 0) ringLDS[t & 3] = aa[0];  // slot t&3: no reader this step
            BAR();
        }

        // ---- logZ epilogue (exact max) ----
        const int freeb = L & 1;   // unused state buffer
        if (ig == 0) {
            f32x4 av = {aa[0], aa[1], aa[2], aa[3]};
            *(f32x4*)(stateLDS + freeb * SPITCH + PI(j0)) = av;
        }
        __syncthreads();
        float fval = -3.4e38f;
        if (tid < 128) fval = stateLDS[freeb * SPITCH + PI(tid)] + endT[tid];
        float tmx = fval;
#pragma unroll
        for (int off = 1; off < 64; off <<= 1) tmx = fmaxf(tmx, __shfl_xor(tmx, off));
        if ((tid & 63) == 0) redLDS[4 + (tid >> 6)] = tmx;
        __syncthreads();
        const float gm = fmaxf(redLDS[4], redLDS[5]);
        float se = (tid < 128) ? __expf(fval - gm) : 0.f;
#pragma unroll
        for (int off = 1; off < 64; off <<= 1) se += __shfl_xor(se, off);
        if ((tid & 63) == 0) sumLDS[tid >> 6] = se;
        __syncthreads();
        if (tid == 0)
            scr_logZ[b] = gm + __logf(sumLDS[0] + sumLDS[1] + sumLDS[2] + sumLDS[3]);
        __syncthreads();

        // ---- numerator (gold path score) ----
        float acc = 0.f;
        for (int t = tid; t < L; t += 256) {
            int tg = target[b * SS + t];
            acc += logit[((size_t)b * SS + t) * TT + tg];
            if (t >= 1) acc += trans[target[b * SS + t - 1] * TT + tg];
        }
#pragma unroll
        for (int off = 1; off < 64; off <<= 1) acc += __shfl_xor(acc, off);
        if ((tid & 63) == 0) sumLDS[tid >> 6] = acc;
        __syncthreads();
        if (tid == 0) {
            float tot = sumLDS[0] + sumLDS[1] + sumLDS[2] + sumLDS[3];
            tot += startT[target[b * SS]] + endT[target[b * SS + L - 1]];
            scr_num[b] = tot;
        }
    }
}

// ---------------- phase 2: per-segment parallel backtrace of all 128 end-tags ----------------
__global__ void crf_btseg(uint8_t* __restrict__ histG)
{
    const int c = blockIdx.x;    // segment 0..31
    const int b = blockIdx.y;    // batch
    const int tid = threadIdx.x; // 128
    __shared__ __align__(16) uint8_t hl[SEGK * TT];

    const int lo = (c == 0) ? 1 : c * SEGK;
    const int nr = (c == 0) ? 63 : 64;
    const uint8_t* src = histG + (size_t)b * (SS * TT) + (size_t)lo * TT;
    for (int k = tid; k < (nr * TT) / 16; k += 128)
        ((uint4*)hl)[k] = ((const uint4*)src)[k];
    __syncthreads();

    int tau = tid;
    uint32_t w[16];
#pragma unroll
    for (int q = 0; q < 16; ++q) w[q] = 0u;
    if (c == 0) {
#pragma unroll
        for (int r = 62; r >= 0; --r) {
            tau = hl[r * TT + tau];
            w[r >> 2] |= ((uint32_t)tau) << ((r & 3) * 8);
        }
    } else {
#pragma unroll
        for (int r = 63; r >= 0; --r) {
            tau = hl[r * TT + tau];
            w[r >> 2] |= ((uint32_t)tau) << ((r & 3) * 8);
        }
    }
    uint4* dst = (uint4*)(histG + (size_t)b * (SS * TT) + (size_t)c * 8192 + (size_t)tid * 64);
    dst[0] = make_uint4(w[0], w[1], w[2], w[3]);
    dst[1] = make_uint4(w[4], w[5], w[6], w[7]);
    dst[2] = make_uint4(w[8], w[9], w[10], w[11]);
    dst[3] = make_uint4(w[12], w[13], w[14], w[15]);
}

// ---------------- phase 3: serial chain over 32 segment maps per batch ----------------
__global__ void crf_btchain(const uint8_t* __restrict__ histG,
                            const int* __restrict__ scr_last,
                            int* __restrict__ scr_bt,
                            float* __restrict__ out_pred)
{
    const int b = threadIdx.x;
    if (b >= BB) return;
    int tau = scr_last[b];
    out_pred[(size_t)b * SS + (SS - 1)] = (float)tau;
    for (int c = NSEG - 1; c >= 0; --c) {
        scr_bt[b * NSEG + c] = tau;
        tau = histG[(size_t)b * (SS * TT) + (size_t)c * 8192 + (size_t)tau * 64];
    }
}

// ---------------- phase 4: parallel fill of pred from chosen paths ----------------
__global__ void crf_btfill(const uint8_t* __restrict__ histG,
                           const int* __restrict__ scr_bt,
                           float* __restrict__ out_pred)
{
    const int c = blockIdx.x;
    const int b = blockIdx.y;
    const int s = threadIdx.x;   // 64
    if (c == 0 && s > 62) return;
    const int js = scr_bt[b * NSEG + c];
    uint8_t v = histG[(size_t)b * (SS * TT) + (size_t)c * 8192 + (size_t)js * 64 + s];
    const int pos = (c == 0) ? s : (c * SEGK - 1 + s);
    out_pred[(size_t)b * SS + pos] = (float)v;
}

// ---------------- loss = mean(logZ - num) ----------------
__global__ void crf_loss(const float* __restrict__ scr_logZ, const float* __restrict__ scr_num,
                         float* __restrict__ out)
{
    const int tid = threadIdx.x; // 128
    __shared__ float p2[2];
    float v = (tid < BB) ? (scr_logZ[tid] - scr_num[tid]) : 0.0f;
#pragma unroll
    for (int off = 1; off < 64; off <<= 1) v += __shfl_xor(v, off);
    if ((tid & 63) == 0) p2[tid >> 6] = v;
    __syncthreads();
    if (tid == 0) out[0] = (p2[0] + p2[1]) / (float)BB;
}

// ---------------- log_probs: swap + log_softmax, one wave per row ----------------
__global__ void crf_logprobs(const float* __restrict__ logit,
                             const float* __restrict__ predF,
                             float* __restrict__ outLP)
{
    const int wid = threadIdx.x >> 6;
    const int lane = threadIdx.x & 63;
    const size_t row = (size_t)blockIdx.x * 4 + wid;
    const float2* rp = (const float2*)(logit + row * TT);
    float2 v = rp[lane];
    const int pred = (int)predF[row];

    float mv; int mi;
    if (v.y > v.x) { mv = v.y; mi = lane * 2 + 1; }
    else           { mv = v.x; mi = lane * 2; }
#pragma unroll
    for (int off = 1; off < 64; off <<= 1) {
        float ov = __shfl_xor(mv, off);
        int oi = __shfl_xor(mi, off);
        if (ov > mv || (ov == mv && oi < mi)) { mv = ov; mi = oi; }
    }
    float se = __expf(v.x - mv) + __expf(v.y - mv);
#pragma unroll
    for (int off = 1; off < 64; off <<= 1) se += __shfl_xor(se, off);
    const float lse = __logf(se);

    float px = __shfl(v.x, pred >> 1);
    float py = __shfl(v.y, pred >> 1);
    float vp = (pred & 1) ? py : px;

    float ox = (lane * 2 == pred) ? mv : ((lane * 2 == mi) ? vp : v.x);
    float oy = (lane * 2 + 1 == pred) ? mv : ((lane * 2 + 1 == mi) ? vp : v.y);
    float* op = outLP + row * TT + lane * 2;
    op[0] = (ox - mv) - lse;
    op[1] = (oy - mv) - lse;
}

extern "C" void kernel_launch(void* const* d_in, const int* in_sizes, int n_in,
                              void* d_out, int out_size, void* d_ws, size_t ws_size,
                              hipStream_t stream)
{
    const float* logit    = (const float*)d_in[0];
    const int*   target   = (const int*)d_in[1];
    const int*   seq_lens = (const int*)d_in[2];
    const float* trans    = (const float*)d_in[3];
    const float* startT   = (const float*)d_in[4];
    const float* endT     = (const float*)d_in[5];

    float* out      = (float*)d_out;
    float* out_pred = out + 1;
    float* outLP    = out + 1 + (size_t)BB * SS;                 // 262145
    uint8_t* histG  = (uint8_t*)(out + 262148);                  // 16B-aligned, 33.5MB
    float* scr      = out + ((size_t)1 + (size_t)BB * SS + (size_t)BB * SS * TT - 4480);
    float* scr_logZ = scr;                // 128
    float* scr_num  = scr + 128;          // 128
    int*   scr_last = (int*)(scr + 256);  // 128
    int*   scr_bt   = (int*)(scr + 384);  // 128*32

    const int dynLDS = 16852 * 4;  // ~67.4KB
    hipFuncSetAttribute((const void*)crf_mainX,
                        hipFuncAttributeMaxDynamicSharedMemorySize, dynLDS);

    crf_mainX<<<2 * BB, 256, dynLDS, stream>>>(logit, seq_lens, trans, startT, endT,
                                               target, histG, scr_logZ, scr_last, scr_num);
    crf_btseg<<<dim3(NSEG, BB), 128, 0, stream>>>(histG);
    crf_btchain<<<1, 128, 0, stream>>>(histG, scr_last, scr_bt, out_pred);
    crf_btfill<<<dim3(NSEG, BB), 64, 0, stream>>>(histG, scr_bt, out_pred);
    crf_loss<<<1, 128, 0, stream>>>(scr_logZ, scr_num, out);
    crf_logprobs<<<(BB * SS) / 4, 256, 0, stream>>>(logit, out_pred, outLP);
}

// Round 6
// 1506.386 us; speedup vs baseline: 1.2500x; 1.2500x over previous
//
#include <hip/hip_runtime.h>
#include <stdint.h>

#define BB 128
#define SS 2048
#define TT 128
#define NSEG 32
#define SEGK 64

// padded layouts (bank-conflict-free, validated R4)
#define TRP 129              // trans row stride (129 % 32 == 1)
#define VSTRIDE 136          // state buffer stride
#define H1OFF 68             // half-1 offset (68 % 32 == 4 -> disjoint banks vs half-0)

typedef float f32x4 __attribute__((ext_vector_type(4)));

// raw barrier: drain LDS ops only (NOT vmcnt -> prefetch loads stay in flight)
#define BAR() asm volatile("s_waitcnt lgkmcnt(0)\n\ts_barrier" ::: "memory")
#define PIN(x) asm volatile("" : "+v"(x))

__device__ __forceinline__ float dpp_swap1_f(float x) {
    int i = __float_as_int(x);
    i = __builtin_amdgcn_update_dpp(0, i, 0xB1, 0xF, 0xF, true);
    return __int_as_float(i);
}
__device__ __forceinline__ int dpp_swap1_i(int x) {
    return __builtin_amdgcn_update_dpp(0, x, 0xB1, 0xF, 0xF, true);
}

#define CLAMPROW(k) (((k) < L) ? (k) : (L - 1))

// one viterbi step; EREG consumed (row tt), refilled with row tt+4 (4-deep pipeline)
#define VSTEP(tt, CURP, EREG)                                                 \
{                                                                             \
    const int cur_ = (CURP), nxt_ = 1 - cur_;                                 \
    const float e_ = EREG;                                                    \
    EREG = logit[lbase + (size_t)CLAMPROW((tt) + 4) * TT + j];                \
    const f32x4* sq_ = (const f32x4*)(vecLDS + cur_ * VSTRIDE + h * H1OFF);   \
    float cm_[8];                                                             \
    _Pragma("unroll")                                                         \
    for (int c = 0; c < 8; ++c) {                                             \
        f32x4 pa = sq_[2 * c] + tC[2 * c];                                    \
        f32x4 pb = sq_[2 * c + 1] + tC[2 * c + 1];                            \
        float m01 = fmaxf(pa.x, pa.y), m23 = fmaxf(pa.z, pa.w);               \
        float m45 = fmaxf(pb.x, pb.y), m67 = fmaxf(pb.z, pb.w);               \
        cm_[c] = fmaxf(fmaxf(m01, m23), fmaxf(m45, m67));                     \
    }                                                                         \
    float M_ = fmaxf(fmaxf(fmaxf(cm_[0], cm_[1]), fmaxf(cm_[2], cm_[3])),     \
                     fmaxf(fmaxf(cm_[4], cm_[5]), fmaxf(cm_[6], cm_[7])));    \
    const float Mall_ = fmaxf(M_, dpp_swap1_f(M_));                           \
    const float v_ = Mall_ + e_;   /* exact reference max value */            \
    int cwin_ = -1;                                                           \
    _Pragma("unroll")                                                         \
    for (int c = 7; c >= 0; --c) cwin_ = ((cm_[c] + e_) == v_) ? c : cwin_;   \
    int idx_ = 0x7fffffff;                                                    \
    if (cwin_ >= 0) {                                                         \
        const int basei_ = ibase0 + cwin_ * 8;                                \
        const float* tr_ = transLDS + (size_t)basei_ * TRP + j;               \
        const f32x4* sr_ = (const f32x4*)(vecLDS + cur_ * VSTRIDE + h * H1OFF + cwin_ * 8); \
        f32x4 ra_ = sr_[0], rb_ = sr_[1];                                     \
        float q0 = (ra_.x + tr_[0 * TRP]) + e_;                               \
        float q1 = (ra_.y + tr_[1 * TRP]) + e_;                               \
        float q2 = (ra_.z + tr_[2 * TRP]) + e_;                               \
        float q3 = (ra_.w + tr_[3 * TRP]) + e_;                               \
        float q4 = (rb_.x + tr_[4 * TRP]) + e_;                               \
        float q5 = (rb_.y + tr_[5 * TRP]) + e_;                               \
        float q6 = (rb_.z + tr_[6 * TRP]) + e_;                               \
        float q7 = (rb_.w + tr_[7 * TRP]) + e_;                               \
        idx_ = (q7 == v_) ? basei_ + 7 : idx_;                                \
        idx_ = (q6 == v_) ? basei_ + 6 : idx_;                                \
        idx_ = (q5 == v_) ? basei_ + 5 : idx_;                                \
        idx_ = (q4 == v_) ? basei_ + 4 : idx_;                                \
        idx_ = (q3 == v_) ? basei_ + 3 : idx_;                                \
        idx_ = (q2 == v_) ? basei_ + 2 : idx_;                                \
        idx_ = (q1 == v_) ? basei_ + 1 : idx_;                                \
        idx_ = (q0 == v_) ? basei_ + 0 : idx_;                                \
    }                                                                         \
    const int oidx_ = dpp_swap1_i(idx_);                                      \
    idx_ = (oidx_ < idx_) ? oidx_ : idx_;  /* first-index across halves */    \
    if (h == 0) {                                                             \
        vecLDS[nxt_ * VSTRIDE + joff] = v_;                                   \
        hb[(size_t)(tt) * TT + j] = (uint8_t)idx_;                            \
    }                                                                         \
    BAR();                                                                    \
}

// one forward step; same 4-deep prefetch discipline
#define FSTEP(tt, CURP, EREG)                                                 \
{                                                                             \
    const int cur_ = (CURP), nxt_ = 1 - cur_;                                 \
    const float Rcons_ = ringLDS[((tt) - 3) & 3];                             \
    const float Rpub_  = ringLDS[((tt) - 2) & 3];                             \
    const float e_ = EREG;                                                    \
    EREG = logit[lbase + (size_t)CLAMPROW((tt) + 4) * TT + j];                \
    const f32x4* aq_ = (const f32x4*)(vecLDS + cur_ * VSTRIDE + h * H1OFF);   \
    f32x4 s4_ = {0.f, 0.f, 0.f, 0.f}, s4b_ = {0.f, 0.f, 0.f, 0.f};            \
    _Pragma("unroll")                                                         \
    for (int c = 0; c < 16; c += 2) {                                         \
        s4_  = aq_[c] * tE[c] + s4_;                                          \
        s4b_ = aq_[c + 1] * tE[c + 1] + s4b_;                                 \
    }                                                                         \
    f32x4 st_ = s4_ + s4b_;                                                   \
    float Ssum_ = (st_.x + st_.y) + (st_.z + st_.w);                          \
    Ssum_ += dpp_swap1_f(Ssum_);                                              \
    alpha = e_ + Rcons_ + __logf(Ssum_);                                      \
    const float p_ = __expf(alpha - Rpub_);                                   \
    if (h == 0) vecLDS[nxt_ * VSTRIDE + joff] = p_;                           \
    if (tid == 0) ringLDS[(tt) & 3] = alpha;                                  \
    BAR();                                                                    \
}

// ---------------- main kernel: 256 blocks. role 0 = viterbi, role 1 = forward+num.
// 256 threads: j=tid>>1, h=tid&1 owns i-half [64h,64h+64). ----------------
__attribute__((amdgpu_flat_work_group_size(256, 256)))
__attribute__((amdgpu_waves_per_eu(1, 1)))
__global__ void crf_mainX(const float* __restrict__ logit,
                          const int* __restrict__ seq_lens,
                          const float* __restrict__ trans,
                          const float* __restrict__ startT,
                          const float* __restrict__ endT,
                          const int* __restrict__ target,
                          uint8_t* __restrict__ histG,
                          float* __restrict__ scr_logZ,
                          int* __restrict__ scr_last,
                          float* __restrict__ scr_num)
{
    extern __shared__ float smem[];
    float* transLDS = smem;                         // 16512 floats
    float* vecLDS   = smem + 16512;                 // 2 * VSTRIDE = 272
    float* ringLDS  = smem + 16512 + 272;           // 4
    float* redLDS   = smem + 16512 + 276;           // 8
    int*   redILDS  = (int*)(smem + 16512 + 284);   // 4
    float* sumLDS   = smem + 16512 + 288;           // 4

    const int bid = blockIdx.x;
    const int role = bid >> 7;
    const int b = bid & (BB - 1);
    const int tid = threadIdx.x;
    const int j = tid >> 1;
    const int h = tid & 1;
    const int ibase0 = h << 6;
    const int joff = j + ((j >= 64) ? (H1OFF - 64) : 0);
    const int L = seq_lens[b];
    const size_t lbase = (size_t)b * (SS * TT);

    // stage transitions into padded LDS (stride TRP)
    for (int m = tid; m < TT * TT; m += 256)
        transLDS[(m >> 7) * TRP + (m & 127)] = trans[m];
    __syncthreads();

    // 4-deep rotating prefetch registers (rows 1..4, clamped)
    float e_a = logit[lbase + (size_t)CLAMPROW(1) * TT + j];
    float e_b = logit[lbase + (size_t)CLAMPROW(2) * TT + j];
    float e_c = logit[lbase + (size_t)CLAMPROW(3) * TT + j];
    float e_d = logit[lbase + (size_t)CLAMPROW(4) * TT + j];

    if (role == 0) {
        // =================== VITERBI ===================
        f32x4 tC[16];  // trans[i][j] for my i-half, pinned in VGPRs
#pragma unroll
        for (int c = 0; c < 16; ++c) {
            tC[c].x = transLDS[(ibase0 + c * 4 + 0) * TRP + j];
            tC[c].y = transLDS[(ibase0 + c * 4 + 1) * TRP + j];
            tC[c].z = transLDS[(ibase0 + c * 4 + 2) * TRP + j];
            tC[c].w = transLDS[(ibase0 + c * 4 + 3) * TRP + j];
            PIN(tC[c]);
        }
        const float a0 = startT[j] + logit[lbase + j];
        if (h == 0) vecLDS[joff] = a0;
        __syncthreads();

        uint8_t* hb = histG + (size_t)b * (SS * TT);

        // steady state: 4 steps/iteration, static parity (t starts at 1, step 4)
        int t = 1;
        for (; t + 3 < L; t += 4) {
            VSTEP(t + 0, 0, e_a);
            VSTEP(t + 1, 1, e_b);
            VSTEP(t + 2, 0, e_c);
            VSTEP(t + 3, 1, e_d);
        }
        // tail (<=3 steps), dynamic parity, rotate registers
        for (; t < L; ++t) {
            VSTEP(t, ((t - 1) & 1), e_a);
            e_a = e_b; e_b = e_c; e_c = e_d;
        }

        // ---- last_tag = argmax_j(score + end), first-index ----
        const int fin = (L - 1) & 1;
        if (tid < 128) {
            const int toff = tid + ((tid >= 64) ? (H1OFF - 64) : 0);
            float lv = vecLDS[fin * VSTRIDE + toff] + endT[tid];
            int li = tid;
#pragma unroll
            for (int off = 1; off < 64; off <<= 1) {
                float ov = __shfl_xor(lv, off);
                int oi = __shfl_xor(li, off);
                if (ov > lv || (ov == lv && oi < li)) { lv = ov; li = oi; }
            }
            if ((tid & 63) == 0) { redLDS[tid >> 6] = lv; redILDS[tid >> 6] = li; }
        }
        __syncthreads();
        if (tid == 0) {
            int lt = (redLDS[1] > redLDS[0] ||
                      (redLDS[1] == redLDS[0] && redILDS[1] < redILDS[0]))
                     ? redILDS[1] : redILDS[0];
            scr_last[b] = lt;
        }
        // ---- identity fill of hist rows [L, SS) ----
        const int colq = (tid & 7) * 16;
        const uint32_t w0 = 0x03020100u + 0x01010101u * (uint32_t)colq;
        const uint4 pat = make_uint4(w0, w0 + 0x04040404u, w0 + 0x08080808u, w0 + 0x0C0C0C0Cu);
        for (int t0 = L; t0 < SS; t0 += 32) {
            int tt = t0 + (tid >> 3);
            if (tt < SS) *(uint4*)(hb + (size_t)tt * TT + colq) = pat;
        }
    } else {
        // =================== FORWARD (logZ) ===================
        f32x4 tE[16];  // exp(trans[i][j]), pinned
#pragma unroll
        for (int c = 0; c < 16; ++c) {
            tE[c].x = __expf(transLDS[(ibase0 + c * 4 + 0) * TRP + j]);
            tE[c].y = __expf(transLDS[(ibase0 + c * 4 + 1) * TRP + j]);
            tE[c].z = __expf(transLDS[(ibase0 + c * 4 + 2) * TRP + j]);
            tE[c].w = __expf(transLDS[(ibase0 + c * 4 + 3) * TRP + j]);
            PIN(tE[c]);
        }
        const float a0 = startT[j] + logit[lbase + j];
        const float R0 = startT[0] + logit[lbase + 0];  // alpha0[0], uniform
        float alpha = a0;
        if (h == 0) vecLDS[joff] = __expf(a0 - R0);
        if (tid < 4) ringLDS[tid] = R0;
        __syncthreads();

        int t = 1;
        for (; t + 3 < L; t += 4) {
            FSTEP(t + 0, 0, e_a);
            FSTEP(t + 1, 1, e_b);
            FSTEP(t + 2, 0, e_c);
            FSTEP(t + 3, 1, e_d);
        }
        for (; t < L; ++t) {
            FSTEP(t, ((t - 1) & 1), e_a);
            e_a = e_b; e_b = e_c; e_c = e_d;
        }

        // ---- logZ epilogue (exact max) ----
        const float fval = alpha + endT[j];
        float tmx = fval;
#pragma unroll
        for (int off = 1; off < 64; off <<= 1) tmx = fmaxf(tmx, __shfl_xor(tmx, off));
        if ((tid & 63) == 0) redLDS[4 + (tid >> 6)] = tmx;
        __syncthreads();
        const float gm = fmaxf(fmaxf(redLDS[4], redLDS[5]), fmaxf(redLDS[6], redLDS[7]));
        float se = (h == 0) ? __expf(fval - gm) : 0.f;
#pragma unroll
        for (int off = 1; off < 64; off <<= 1) se += __shfl_xor(se, off);
        if ((tid & 63) == 0) sumLDS[tid >> 6] = se;
        __syncthreads();
        if (tid == 0)
            scr_logZ[b] = gm + __logf(sumLDS[0] + sumLDS[1] + sumLDS[2] + sumLDS[3]);
        __syncthreads();

        // ---- numerator (gold path score) ----
        float acc = 0.f;
        for (int tt = tid; tt < L; tt += 256) {
            int tg = target[b * SS + tt];
            acc += logit[((size_t)b * SS + tt) * TT + tg];
            if (tt >= 1) acc += trans[target[b * SS + tt - 1] * TT + tg];
        }
#pragma unroll
        for (int off = 1; off < 64; off <<= 1) acc += __shfl_xor(acc, off);
        if ((tid & 63) == 0) sumLDS[tid >> 6] = acc;
        __syncthreads();
        if (tid == 0) {
            float tot = sumLDS[0] + sumLDS[1] + sumLDS[2] + sumLDS[3];
            tot += startT[target[b * SS]] + endT[target[b * SS + L - 1]];
            scr_num[b] = tot;
        }
    }
}

// ---------------- phase 2: per-segment parallel backtrace of all 128 end-tags ----------------
__global__ void crf_btseg(uint8_t* __restrict__ histG)
{
    const int c = blockIdx.x;    // segment 0..31
    const int b = blockIdx.y;    // batch
    const int tid = threadIdx.x; // 128
    __shared__ __align__(16) uint8_t hl[SEGK * TT];

    const int lo = (c == 0) ? 1 : c * SEGK;
    const int nr = (c == 0) ? 63 : 64;
    const uint8_t* src = histG + (size_t)b * (SS * TT) + (size_t)lo * TT;
    for (int k = tid; k < (nr * TT) / 16; k += 128)
        ((uint4*)hl)[k] = ((const uint4*)src)[k];
    __syncthreads();

    int tau = tid;
    uint32_t w[16];
#pragma unroll
    for (int q = 0; q < 16; ++q) w[q] = 0u;
    if (c == 0) {
#pragma unroll
        for (int r = 62; r >= 0; --r) {
            tau = hl[r * TT + tau];
            w[r >> 2] |= ((uint32_t)tau) << ((r & 3) * 8);
        }
    } else {
#pragma unroll
        for (int r = 63; r >= 0; --r) {
            tau = hl[r * TT + tau];
            w[r >> 2] |= ((uint32_t)tau) << ((r & 3) * 8);
        }
    }
    uint4* dst = (uint4*)(histG + (size_t)b * (SS * TT) + (size_t)c * 8192 + (size_t)tid * 64);
    dst[0] = make_uint4(w[0], w[1], w[2], w[3]);
    dst[1] = make_uint4(w[4], w[5], w[6], w[7]);
    dst[2] = make_uint4(w[8], w[9], w[10], w[11]);
    dst[3] = make_uint4(w[12], w[13], w[14], w[15]);
}

// ---------------- phase 3: serial chain over 32 segment maps per batch ----------------
__global__ void crf_btchain(const uint8_t* __restrict__ histG,
                            const int* __restrict__ scr_last,
                            int* __restrict__ scr_bt,
                            float* __restrict__ out_pred)
{
    const int b = threadIdx.x;
    if (b >= BB) return;
    int tau = scr_last[b];
    out_pred[(size_t)b * SS + (SS - 1)] = (float)tau;
    for (int c = NSEG - 1; c >= 0; --c) {
        scr_bt[b * NSEG + c] = tau;
        tau = histG[(size_t)b * (SS * TT) + (size_t)c * 8192 + (size_t)tau * 64];
    }
}

// ---------------- phase 4: parallel fill of pred from chosen paths ----------------
__global__ void crf_btfill(const uint8_t* __restrict__ histG,
                           const int* __restrict__ scr_bt,
                           float* __restrict__ out_pred)
{
    const int c = blockIdx.x;
    const int b = blockIdx.y;
    const int s = threadIdx.x;   // 64
    if (c == 0 && s > 62) return;
    const int js = scr_bt[b * NSEG + c];
    uint8_t v = histG[(size_t)b * (SS * TT) + (size_t)c * 8192 + (size_t)js * 64 + s];
    const int pos = (c == 0) ? s : (c * SEGK - 1 + s);
    out_pred[(size_t)b * SS + pos] = (float)v;
}

// ---------------- loss = mean(logZ - num) ----------------
__global__ void crf_loss(const float* __restrict__ scr_logZ, const float* __restrict__ scr_num,
                         float* __restrict__ out)
{
    const int tid = threadIdx.x; // 128
    __shared__ float p2[2];
    float v = (tid < BB) ? (scr_logZ[tid] - scr_num[tid]) : 0.0f;
#pragma unroll
    for (int off = 1; off < 64; off <<= 1) v += __shfl_xor(v, off);
    if ((tid & 63) == 0) p2[tid >> 6] = v;
    __syncthreads();
    if (tid == 0) out[0] = (p2[0] + p2[1]) / (float)BB;
}

// ---------------- log_probs: swap + log_softmax, one wave per row ----------------
__global__ void crf_logprobs(const float* __restrict__ logit,
                             const float* __restrict__ predF,
                             float* __restrict__ outLP)
{
    const int wid = threadIdx.x >> 6;
    const int lane = threadIdx.x & 63;
    const size_t row = (size_t)blockIdx.x * 4 + wid;
    const float2* rp = (const float2*)(logit + row * TT);
    float2 v = rp[lane];
    const int pred = (int)predF[row];

    float mv; int mi;
    if (v.y > v.x) { mv = v.y; mi = lane * 2 + 1; }
    else           { mv = v.x; mi = lane * 2; }
#pragma unroll
    for (int off = 1; off < 64; off <<= 1) {
        float ov = __shfl_xor(mv, off);
        int oi = __shfl_xor(mi, off);
        if (ov > mv || (ov == mv && oi < mi)) { mv = ov; mi = oi; }
    }
    float se = __expf(v.x - mv) + __expf(v.y - mv);
#pragma unroll
    for (int off = 1; off < 64; off <<= 1) se += __shfl_xor(se, off);
    const float lse = __logf(se);

    float px = __shfl(v.x, pred >> 1);
    float py = __shfl(v.y, pred >> 1);
    float vp = (pred & 1) ? py : px;

    float ox = (lane * 2 == pred) ? mv : ((lane * 2 == mi) ? vp : v.x);
    float oy = (lane * 2 + 1 == pred) ? mv : ((lane * 2 + 1 == mi) ? vp : v.y);
    float* op = outLP + row * TT + lane * 2;
    op[0] = (ox - mv) - lse;
    op[1] = (oy - mv) - lse;
}

extern "C" void kernel_launch(void* const* d_in, const int* in_sizes, int n_in,
                              void* d_out, int out_size, void* d_ws, size_t ws_size,
                              hipStream_t stream)
{
    const float* logit    = (const float*)d_in[0];
    const int*   target   = (const int*)d_in[1];
    const int*   seq_lens = (const int*)d_in[2];
    const float* trans    = (const float*)d_in[3];
    const float* startT   = (const float*)d_in[4];
    const float* endT     = (const float*)d_in[5];

    float* out      = (float*)d_out;
    float* out_pred = out + 1;
    float* outLP    = out + 1 + (size_t)BB * SS;                 // 262145
    uint8_t* histG  = (uint8_t*)(out + 262148);                  // 16B-aligned, 33.5MB
    float* scr      = out + ((size_t)1 + (size_t)BB * SS + (size_t)BB * SS * TT - 4480);
    float* scr_logZ = scr;                // 128
    float* scr_num  = scr + 128;          // 128
    int*   scr_last = (int*)(scr + 256);  // 128
    int*   scr_bt   = (int*)(scr + 384);  // 128*32

    const int dynLDS = (16512 + 292) * 4;  // ~67.2KB
    hipFuncSetAttribute((const void*)crf_mainX,
                        hipFuncAttributeMaxDynamicSharedMemorySize, dynLDS);

    crf_mainX<<<2 * BB, 256, dynLDS, stream>>>(logit, seq_lens, trans, startT, endT,
                                               target, histG, scr_logZ, scr_last, scr_num);
    crf_btseg<<<dim3(NSEG, BB), 128, 0, stream>>>(histG);
    crf_btchain<<<1, 128, 0, stream>>>(histG, scr_last, scr_bt, out_pred);
    crf_btfill<<<dim3(NSEG, BB), 64, 0, stream>>>(histG, scr_bt, out_pred);
    crf_loss<<<1, 128, 0, stream>>>(scr_logZ, scr_num, out);
    crf_logprobs<<<(BB * SS) / 4, 256, 0, stream>>>(logit, out_pred, outLP);
}